// Round 2
// baseline (402.996 us; speedup 1.0000x reference)
//
#include <hip/hip_runtime.h>
#include <hip/hip_bf16.h>

#define IN_DIM 128
#define OUT_DIM 64
#define NPW 8  // nodes per wave in proj (N=50000 not divisible by 8 -> guarded)

// K1: projection + attention partials. Each wave handles NPW nodes; lane = out dim.
// h-row loads are wave-uniform (readfirstlane) -> scalar loads through sL1,
// W loads are shared across the NPW nodes (L1 traffic per node / NPW).
__global__ __launch_bounds__(256) void gat_proj(
    const float* __restrict__ h, const float* __restrict__ W,
    const float* __restrict__ Wb, const float* __restrict__ Aw,
    float* __restrict__ Wh, float* __restrict__ a_dst_arr,
    float* __restrict__ a_src_arr, int N)
{
    int wid  = (int)((blockIdx.x * blockDim.x + threadIdx.x) >> 6);
    int lane = threadIdx.x & 63;
    int node0 = __builtin_amdgcn_readfirstlane(wid * NPW);
    if (node0 >= N) return;

    float wb  = Wb[lane];
    float awd = Aw[lane];            // A_w[:64]  (dst partial)
    float aws = Aw[OUT_DIM + lane];  // A_w[64:]  (src partial)

    float acc[NPW];
    #pragma unroll
    for (int n = 0; n < NPW; n++) acc[n] = wb;

    const float* __restrict__ hr = h + (size_t)node0 * IN_DIM;
    const bool full = (node0 + NPW <= N);

    if (full) {
        for (int k = 0; k < IN_DIM; k += 4) {
            float w0 = W[(k + 0) * OUT_DIM + lane];
            float w1 = W[(k + 1) * OUT_DIM + lane];
            float w2 = W[(k + 2) * OUT_DIM + lane];
            float w3 = W[(k + 3) * OUT_DIM + lane];
            #pragma unroll
            for (int n = 0; n < NPW; n++) {
                float4 h4 = *(const float4*)(hr + (size_t)n * IN_DIM + k); // uniform -> s_load
                acc[n] = fmaf(h4.x, w0, acc[n]);
                acc[n] = fmaf(h4.y, w1, acc[n]);
                acc[n] = fmaf(h4.z, w2, acc[n]);
                acc[n] = fmaf(h4.w, w3, acc[n]);
            }
        }
    } else {
        int nmax = N - node0;
        for (int k = 0; k < IN_DIM; k += 4) {
            float w0 = W[(k + 0) * OUT_DIM + lane];
            float w1 = W[(k + 1) * OUT_DIM + lane];
            float w2 = W[(k + 2) * OUT_DIM + lane];
            float w3 = W[(k + 3) * OUT_DIM + lane];
            for (int n = 0; n < nmax; n++) {
                float4 h4 = *(const float4*)(hr + (size_t)n * IN_DIM + k);
                acc[n] = fmaf(h4.x, w0, acc[n]);
                acc[n] = fmaf(h4.y, w1, acc[n]);
                acc[n] = fmaf(h4.z, w2, acc[n]);
                acc[n] = fmaf(h4.w, w3, acc[n]);
            }
        }
    }

    #pragma unroll
    for (int n = 0; n < NPW; n++) {
        int node = node0 + n;
        if (node >= N) break;
        Wh[(size_t)node * OUT_DIM + lane] = acc[n];
        float pd = acc[n] * awd;
        float ps = acc[n] * aws;
        #pragma unroll
        for (int off = 1; off < 64; off <<= 1) {
            pd += __shfl_xor(pd, off);
            ps += __shfl_xor(ps, off);
        }
        if (lane == 0) {
            a_dst_arr[node] = pd;
            a_src_arr[node] = ps;
        }
    }
}

// K2: per-edge logits -> den accumulation + dst histogram. (Max-subtraction
// skipped: alpha invariant, e bounded.)
__global__ __launch_bounds__(256) void gat_edge_hist(
    const int* __restrict__ src, const int* __restrict__ dst,
    const float* __restrict__ a_dst_arr, const float* __restrict__ a_src_arr,
    const float* __restrict__ Ab,
    float* __restrict__ den, int* __restrict__ cnt, int E)
{
    int e = (int)(blockIdx.x * blockDim.x + threadIdx.x);
    if (e >= E) return;
    int s = src[e];
    int t = dst[e];
    float v = a_dst_arr[t] + a_src_arr[s] + Ab[0];
    v = (v > 0.0f) ? v : 0.2f * v;
    atomicAdd(&den[t], __expf(v));
    atomicAdd(&cnt[t], 1);
}

// K3: single-block exclusive scan of cnt -> offs (and cursor copy).
__global__ __launch_bounds__(1024) void gat_scan(
    const int* __restrict__ cnt, int* __restrict__ offs,
    int* __restrict__ cursor, int N)
{
    __shared__ int partial[1024];
    int t = threadIdx.x;
    int chunk = (N + 1023) >> 10;
    int beg = t * chunk;
    int end = min(beg + chunk, N);
    int s = 0;
    for (int i = beg; i < end; i++) s += cnt[i];
    partial[t] = s;
    __syncthreads();
    for (int off = 1; off < 1024; off <<= 1) {
        int v = partial[t];
        int add = (t >= off) ? partial[t - off] : 0;
        __syncthreads();
        partial[t] = v + add;
        __syncthreads();
    }
    if (t == 1023) offs[N] = partial[1023];
    int run = (t == 0) ? 0 : partial[t - 1];
    for (int i = beg; i < end; i++) {
        offs[i] = run;
        cursor[i] = run;
        run += cnt[i];
    }
}

// K4: scatter edges into CSR order by dst (recomputes ex; no ex array needed).
__global__ __launch_bounds__(256) void gat_scatter(
    const int* __restrict__ src, const int* __restrict__ dst,
    const float* __restrict__ a_dst_arr, const float* __restrict__ a_src_arr,
    const float* __restrict__ Ab,
    int* __restrict__ cursor, int* __restrict__ csr_src,
    float* __restrict__ csr_w, int E)
{
    int e = (int)(blockIdx.x * blockDim.x + threadIdx.x);
    if (e >= E) return;
    int s = src[e];
    int t = dst[e];
    float v = a_dst_arr[t] + a_src_arr[s] + Ab[0];
    v = (v > 0.0f) ? v : 0.2f * v;
    float x = __expf(v);
    int pos = atomicAdd(&cursor[t], 1);
    csr_src[pos] = s;
    csr_w[pos] = x;
}

// K5: gather-aggregate. One wave per dst node; lane = dim. Single write to out.
__global__ __launch_bounds__(256) void gat_agg(
    const int* __restrict__ offs, const int* __restrict__ csr_src,
    const float* __restrict__ csr_w, const float* __restrict__ den,
    const float* __restrict__ Wh, float* __restrict__ out, int N)
{
    int node = (int)((blockIdx.x * blockDim.x + threadIdx.x) >> 6);
    int lane = threadIdx.x & 63;
    if (node >= N) return;
    int u   = __builtin_amdgcn_readfirstlane(node);
    int beg = offs[u];
    int end = offs[u + 1];
    float acc = 0.0f;
    for (int j = beg; j < end; j++) {
        int   s = csr_src[j];   // wave-uniform -> scalar load
        float w = csr_w[j];
        acc = fmaf(w, Wh[(size_t)s * OUT_DIM + lane], acc);
    }
    float inv = (end > beg) ? 1.0f / den[u] : 0.0f;
    out[(size_t)u * OUT_DIM + lane] = acc * inv;
}

extern "C" void kernel_launch(void* const* d_in, const int* in_sizes, int n_in,
                              void* d_out, int out_size, void* d_ws, size_t ws_size,
                              hipStream_t stream)
{
    const float* h   = (const float*)d_in[0];
    const float* W_w = (const float*)d_in[1];
    const float* W_b = (const float*)d_in[2];
    const float* A_w = (const float*)d_in[3];
    const float* A_b = (const float*)d_in[4];
    const int*   src = (const int*)d_in[5];
    const int*   dst = (const int*)d_in[6];
    float* out = (float*)d_out;

    const int N = in_sizes[0] / IN_DIM;   // 50000
    const int E = in_sizes[5];            // 800000

    // Workspace layout (4 B elems):
    // Wh[N*64] | a_dst[N] | a_src[N] | den[N] | cnt[N] | offs[N+1] | cursor[N]
    // | csr_src[E] | csr_w[E]
    float* ws      = (float*)d_ws;
    float* Wh      = ws;
    float* a_dst_a = Wh + (size_t)N * OUT_DIM;
    float* a_src_a = a_dst_a + N;
    float* den     = a_src_a + N;
    int*   cnt     = (int*)(den + N);
    int*   offs    = cnt + N;
    int*   cursor  = offs + (N + 1);
    int*   csr_src = cursor + N;
    float* csr_w   = (float*)(csr_src + E);

    // Zero den + cnt (contiguous).
    hipMemsetAsync(den, 0, (size_t)2 * N * sizeof(float), stream);

    {   // K1: projection + attention partials
        int waves = (N + NPW - 1) / NPW;
        int grid  = (waves + 3) / 4;   // 4 waves per 256-thread block
        gat_proj<<<grid, 256, 0, stream>>>(h, W_w, W_b, A_w, Wh, a_dst_a, a_src_a, N);
    }
    {   // K2: den + histogram
        int grid = (E + 255) / 256;
        gat_edge_hist<<<grid, 256, 0, stream>>>(src, dst, a_dst_a, a_src_a, A_b, den, cnt, E);
    }
    {   // K3: scan
        gat_scan<<<1, 1024, 0, stream>>>(cnt, offs, cursor, N);
    }
    {   // K4: CSR scatter
        int grid = (E + 255) / 256;
        gat_scatter<<<grid, 256, 0, stream>>>(src, dst, a_dst_a, a_src_a, A_b, cursor,
                                              csr_src, csr_w, E);
    }
    {   // K5: gather-aggregate
        int grid = (N + 3) / 4;        // 4 nodes (waves) per block
        gat_agg<<<grid, 256, 0, stream>>>(offs, csr_src, csr_w, den, Wh, out, N);
    }
}

// Round 3
// 260.379 us; speedup vs baseline: 1.5477x; 1.5477x over previous
//
#include <hip/hip_runtime.h>
#include <hip/hip_bf16.h>

#define IN_DIM 128
#define OUT_DIM 64
#define NPW 8          // nodes per wave in proj
#define SCAN_CHUNK 1024  // elements per block in hierarchical scan

// K1: projection + attention partials. Each wave handles NPW nodes; lane = out dim.
__global__ __launch_bounds__(256) void gat_proj(
    const float* __restrict__ h, const float* __restrict__ W,
    const float* __restrict__ Wb, const float* __restrict__ Aw,
    float* __restrict__ Wh, float* __restrict__ a_dst_arr,
    float* __restrict__ a_src_arr, int N)
{
    int wid  = (int)((blockIdx.x * blockDim.x + threadIdx.x) >> 6);
    int lane = threadIdx.x & 63;
    int node0 = __builtin_amdgcn_readfirstlane(wid * NPW);
    if (node0 >= N) return;

    float wb  = Wb[lane];
    float awd = Aw[lane];            // A_w[:64]  (dst partial)
    float aws = Aw[OUT_DIM + lane];  // A_w[64:]  (src partial)

    float acc[NPW];
    #pragma unroll
    for (int n = 0; n < NPW; n++) acc[n] = wb;

    const float* __restrict__ hr = h + (size_t)node0 * IN_DIM;
    const bool full = (node0 + NPW <= N);

    if (full) {
        for (int k = 0; k < IN_DIM; k += 4) {
            float w0 = W[(k + 0) * OUT_DIM + lane];
            float w1 = W[(k + 1) * OUT_DIM + lane];
            float w2 = W[(k + 2) * OUT_DIM + lane];
            float w3 = W[(k + 3) * OUT_DIM + lane];
            #pragma unroll
            for (int n = 0; n < NPW; n++) {
                float4 h4 = *(const float4*)(hr + (size_t)n * IN_DIM + k);
                acc[n] = fmaf(h4.x, w0, acc[n]);
                acc[n] = fmaf(h4.y, w1, acc[n]);
                acc[n] = fmaf(h4.z, w2, acc[n]);
                acc[n] = fmaf(h4.w, w3, acc[n]);
            }
        }
    } else {
        int nmax = N - node0;
        for (int k = 0; k < IN_DIM; k += 4) {
            float w0 = W[(k + 0) * OUT_DIM + lane];
            float w1 = W[(k + 1) * OUT_DIM + lane];
            float w2 = W[(k + 2) * OUT_DIM + lane];
            float w3 = W[(k + 3) * OUT_DIM + lane];
            for (int n = 0; n < nmax; n++) {
                float4 h4 = *(const float4*)(hr + (size_t)n * IN_DIM + k);
                acc[n] = fmaf(h4.x, w0, acc[n]);
                acc[n] = fmaf(h4.y, w1, acc[n]);
                acc[n] = fmaf(h4.z, w2, acc[n]);
                acc[n] = fmaf(h4.w, w3, acc[n]);
            }
        }
    }

    #pragma unroll
    for (int n = 0; n < NPW; n++) {
        int node = node0 + n;
        if (node >= N) break;
        Wh[(size_t)node * OUT_DIM + lane] = acc[n];
        float pd = acc[n] * awd;
        float ps = acc[n] * aws;
        #pragma unroll
        for (int off = 1; off < 64; off <<= 1) {
            pd += __shfl_xor(pd, off);
            ps += __shfl_xor(ps, off);
        }
        if (lane == 0) {
            a_dst_arr[node] = pd;
            a_src_arr[node] = ps;
        }
    }
}

// K2: per-edge dst histogram only (den is computed later as segment-sum of csr_w).
__global__ __launch_bounds__(256) void gat_hist(
    const int* __restrict__ dst, int* __restrict__ cnt, int E)
{
    int e = (int)(blockIdx.x * blockDim.x + threadIdx.x);
    if (e >= E) return;
    atomicAdd(&cnt[dst[e]], 1);
}

// K3a: per-block sums of cnt (SCAN_CHUNK elements per block, 256 threads x 4).
__global__ __launch_bounds__(256) void gat_scan1(
    const int* __restrict__ cnt, int* __restrict__ bsum, int N)
{
    __shared__ int partial[256];
    int t = threadIdx.x;
    int base = blockIdx.x * SCAN_CHUNK + t * 4;
    int s = 0;
    #pragma unroll
    for (int i = 0; i < 4; i++) {
        int idx = base + i;
        if (idx < N) s += cnt[idx];
    }
    partial[t] = s;
    __syncthreads();
    for (int off = 128; off > 0; off >>= 1) {
        if (t < off) partial[t] += partial[t + off];
        __syncthreads();
    }
    if (t == 0) bsum[blockIdx.x] = partial[0];
}

// K3b: single-block exclusive scan of the block sums (nb <= 1024).
__global__ __launch_bounds__(1024) void gat_scan2(
    const int* __restrict__ bsum, int* __restrict__ bbase,
    int* __restrict__ offs, int nb, int N)
{
    __shared__ int buf[1024];
    int t = threadIdx.x;
    int v = (t < nb) ? bsum[t] : 0;
    buf[t] = v;
    __syncthreads();
    // Hillis-Steele inclusive scan.
    for (int off = 1; off < 1024; off <<= 1) {
        int add = (t >= off) ? buf[t - off] : 0;
        __syncthreads();
        buf[t] += add;
        __syncthreads();
    }
    if (t < nb) bbase[t] = buf[t] - v;   // exclusive
    if (t == nb - 1) offs[N] = buf[t];   // total = E
}

// K3c: per-block exclusive scan of cnt + block base -> offs, cursor.
__global__ __launch_bounds__(256) void gat_scan3(
    const int* __restrict__ cnt, const int* __restrict__ bbase,
    int* __restrict__ offs, int* __restrict__ cursor, int N)
{
    __shared__ int partial[256];
    int t = threadIdx.x;
    int base = blockIdx.x * SCAN_CHUNK + t * 4;
    int c[4];
    int s = 0;
    #pragma unroll
    for (int i = 0; i < 4; i++) {
        int idx = base + i;
        c[i] = (idx < N) ? cnt[idx] : 0;
        s += c[i];
    }
    partial[t] = s;
    __syncthreads();
    for (int off = 1; off < 256; off <<= 1) {
        int add = (t >= off) ? partial[t - off] : 0;
        __syncthreads();
        partial[t] += add;
        __syncthreads();
    }
    int run = bbase[blockIdx.x] + partial[t] - s;  // exclusive prefix for this thread
    #pragma unroll
    for (int i = 0; i < 4; i++) {
        int idx = base + i;
        if (idx < N) {
            offs[idx] = run;
            cursor[idx] = run;
            run += c[i];
        }
    }
}

// K4: scatter edges into CSR order by dst (computes ex inline).
__global__ __launch_bounds__(256) void gat_scatter(
    const int* __restrict__ src, const int* __restrict__ dst,
    const float* __restrict__ a_dst_arr, const float* __restrict__ a_src_arr,
    const float* __restrict__ Ab,
    int* __restrict__ cursor, int* __restrict__ csr_src,
    float* __restrict__ csr_w, int E)
{
    int e = (int)(blockIdx.x * blockDim.x + threadIdx.x);
    if (e >= E) return;
    int s = src[e];
    int t = dst[e];
    float v = a_dst_arr[t] + a_src_arr[s] + Ab[0];
    v = (v > 0.0f) ? v : 0.2f * v;
    float x = __expf(v);
    int pos = atomicAdd(&cursor[t], 1);
    csr_src[pos] = s;
    csr_w[pos] = x;
}

// K5: gather-aggregate. One wave per dst node; lane = dim. wsum = denominator.
__global__ __launch_bounds__(256) void gat_agg(
    const int* __restrict__ offs, const int* __restrict__ csr_src,
    const float* __restrict__ csr_w,
    const float* __restrict__ Wh, float* __restrict__ out, int N)
{
    int node = (int)((blockIdx.x * blockDim.x + threadIdx.x) >> 6);
    int lane = threadIdx.x & 63;
    if (node >= N) return;
    int u   = __builtin_amdgcn_readfirstlane(node);
    int beg = offs[u];
    int end = offs[u + 1];
    float acc = 0.0f;
    float wsum = 0.0f;
    for (int j = beg; j < end; j++) {
        int   s = csr_src[j];   // wave-uniform -> scalar load
        float w = csr_w[j];
        wsum += w;
        acc = fmaf(w, Wh[(size_t)s * OUT_DIM + lane], acc);
    }
    float inv = (end > beg) ? 1.0f / wsum : 0.0f;
    out[(size_t)u * OUT_DIM + lane] = acc * inv;
}

extern "C" void kernel_launch(void* const* d_in, const int* in_sizes, int n_in,
                              void* d_out, int out_size, void* d_ws, size_t ws_size,
                              hipStream_t stream)
{
    const float* h   = (const float*)d_in[0];
    const float* W_w = (const float*)d_in[1];
    const float* W_b = (const float*)d_in[2];
    const float* A_w = (const float*)d_in[3];
    const float* A_b = (const float*)d_in[4];
    const int*   src = (const int*)d_in[5];
    const int*   dst = (const int*)d_in[6];
    float* out = (float*)d_out;

    const int N = in_sizes[0] / IN_DIM;   // 50000
    const int E = in_sizes[5];            // 800000

    const int nb = (N + SCAN_CHUNK - 1) / SCAN_CHUNK;  // 49 scan blocks

    // Workspace layout (4 B elems):
    // Wh[N*64] | a_dst[N] | a_src[N] | cnt[N] | offs[N+1] | cursor[N]
    // | bsum[nb] | bbase[nb] | csr_src[E] | csr_w[E]
    float* ws      = (float*)d_ws;
    float* Wh      = ws;
    float* a_dst_a = Wh + (size_t)N * OUT_DIM;
    float* a_src_a = a_dst_a + N;
    int*   cnt     = (int*)(a_src_a + N);
    int*   offs    = cnt + N;
    int*   cursor  = offs + (N + 1);
    int*   bsum    = cursor + N;
    int*   bbase   = bsum + nb;
    int*   csr_src = bbase + nb;
    float* csr_w   = (float*)(csr_src + E);

    hipMemsetAsync(cnt, 0, (size_t)N * sizeof(int), stream);

    {   // K1: projection + attention partials
        int waves = (N + NPW - 1) / NPW;
        int grid  = (waves + 3) / 4;   // 4 waves per 256-thread block
        gat_proj<<<grid, 256, 0, stream>>>(h, W_w, W_b, A_w, Wh, a_dst_a, a_src_a, N);
    }
    {   // K2: dst histogram
        int grid = (E + 255) / 256;
        gat_hist<<<grid, 256, 0, stream>>>(dst, cnt, E);
    }
    // K3: hierarchical exclusive scan cnt -> offs (+cursor)
    gat_scan1<<<nb, 256, 0, stream>>>(cnt, bsum, N);
    gat_scan2<<<1, 1024, 0, stream>>>(bsum, bbase, offs, nb, N);
    gat_scan3<<<nb, 256, 0, stream>>>(cnt, bbase, offs, cursor, N);
    {   // K4: CSR scatter
        int grid = (E + 255) / 256;
        gat_scatter<<<grid, 256, 0, stream>>>(src, dst, a_dst_a, a_src_a, A_b, cursor,
                                              csr_src, csr_w, E);
    }
    {   // K5: gather-aggregate
        int grid = (N + 3) / 4;        // 4 nodes (waves) per block
        gat_agg<<<grid, 256, 0, stream>>>(offs, csr_src, csr_w, Wh, out, N);
    }
}

// Round 5
// 223.578 us; speedup vs baseline: 1.8025x; 1.1646x over previous
//
#include <hip/hip_runtime.h>
#include <hip/hip_bf16.h>
#include <hip/hip_fp16.h>

#define IN_DIM 128
#define OUT_DIM 64
#define SCAN_CHUNK 1024

typedef __attribute__((ext_vector_type(8))) short short8;
typedef unsigned short ushort_t;
typedef unsigned int uint_t;

__device__ inline float bf16_to_f(ushort_t u) {
    return __uint_as_float(((uint_t)u) << 16);
}
__device__ inline ushort_t f_to_bf16(float f) {
    uint_t x = __float_as_uint(f);
    // round-to-nearest-even on the low 16 bits (finite values only here)
    uint_t r = (x + 0x7fffu + ((x >> 16) & 1u)) >> 16;
    return (ushort_t)r;
}

// ---------------------------------------------------------------------------
// K1: projection. LDS-tiled GEMM: 64 nodes x 64 dims per block (128 threads),
// per-thread tile = 4 nodes x 8 dims. W fully staged (32 KB), h in 32-k chunks.
// Also computes per-node attention partials a_dst/a_src from fp32 accumulators
// and writes Wh in bf16 (consumed only by the aggregate gather).
// ---------------------------------------------------------------------------
#define PROJ_NODES 64
#define PROJ_KC 32
#define HL_STRIDE 36   // 32 + 4 pad dwords

__global__ __launch_bounds__(128) void gat_proj(
    const float* __restrict__ h, const float* __restrict__ W,
    const float* __restrict__ Wb, const float* __restrict__ Aw,
    ushort_t* __restrict__ Whb, float* __restrict__ a_dst_arr,
    float* __restrict__ a_src_arr, int N)
{
    __shared__ float Wl[IN_DIM * OUT_DIM];          // 32 KB
    __shared__ float hl[PROJ_NODES * HL_STRIDE];    // 9.2 KB

    const int t = threadIdx.x;
    const int td = t & 7;     // dim group: dims td*8 .. td*8+7
    const int tn = t >> 3;    // node group: nodes tn*4 .. tn*4+3
    const int d0 = td * 8;
    const int node0 = blockIdx.x * PROJ_NODES;

    // Stage W fully (coalesced float4).
    for (int i = t * 4; i < IN_DIM * OUT_DIM; i += 128 * 4)
        *(float4*)&Wl[i] = *(const float4*)&W[i];

    float wb[8], awd[8], aws[8];
    #pragma unroll
    for (int i = 0; i < 8; i++) {
        wb[i]  = Wb[d0 + i];
        awd[i] = Aw[d0 + i];
        aws[i] = Aw[OUT_DIM + d0 + i];
    }

    float acc[4][8];
    #pragma unroll
    for (int n = 0; n < 4; n++)
        #pragma unroll
        for (int i = 0; i < 8; i++) acc[n][i] = wb[i];

    for (int kc0 = 0; kc0 < IN_DIM; kc0 += PROJ_KC) {
        __syncthreads();
        // Stage h chunk: 64 nodes x 32 k (512 float4 units / 128 threads = 4 each).
        for (int f = t; f < PROJ_NODES * 8; f += 128) {
            int n = f >> 3, k4 = (f & 7) << 2;
            float4 v = make_float4(0.f, 0.f, 0.f, 0.f);
            if (node0 + n < N)
                v = *(const float4*)&h[(size_t)(node0 + n) * IN_DIM + kc0 + k4];
            *(float4*)&hl[n * HL_STRIDE + k4] = v;
        }
        __syncthreads();

        for (int k2 = 0; k2 < PROJ_KC; k2 += 4) {
            float hk[4][4];
            #pragma unroll
            for (int n = 0; n < 4; n++) {
                float4 hv = *(const float4*)&hl[(tn * 4 + n) * HL_STRIDE + k2];
                hk[n][0] = hv.x; hk[n][1] = hv.y; hk[n][2] = hv.z; hk[n][3] = hv.w;
            }
            #pragma unroll
            for (int kk = 0; kk < 4; kk++) {
                const float* wr = &Wl[(kc0 + k2 + kk) * OUT_DIM + d0];
                float4 wA = *(const float4*)&wr[0];
                float4 wB = *(const float4*)&wr[4];
                #pragma unroll
                for (int n = 0; n < 4; n++) {
                    float hv = hk[n][kk];
                    acc[n][0] = fmaf(hv, wA.x, acc[n][0]);
                    acc[n][1] = fmaf(hv, wA.y, acc[n][1]);
                    acc[n][2] = fmaf(hv, wA.z, acc[n][2]);
                    acc[n][3] = fmaf(hv, wA.w, acc[n][3]);
                    acc[n][4] = fmaf(hv, wB.x, acc[n][4]);
                    acc[n][5] = fmaf(hv, wB.y, acc[n][5]);
                    acc[n][6] = fmaf(hv, wB.z, acc[n][6]);
                    acc[n][7] = fmaf(hv, wB.w, acc[n][7]);
                }
            }
        }
    }

    // Epilogue: bf16 Wh store + attention partials (fp32, reduced over td lanes).
    #pragma unroll
    for (int n = 0; n < 4; n++) {
        int node = node0 + tn * 4 + n;
        if (node >= N) continue;
        union { short8 v; ushort_t u[8]; } o;
        float pd = 0.f, ps = 0.f;
        #pragma unroll
        for (int i = 0; i < 8; i++) {
            o.u[i] = f_to_bf16(acc[n][i]);
            pd = fmaf(acc[n][i], awd[i], pd);
            ps = fmaf(acc[n][i], aws[i], ps);
        }
        *(short8*)&Whb[(size_t)node * OUT_DIM + d0] = o.v;
        #pragma unroll
        for (int off = 1; off < 8; off <<= 1) {
            pd += __shfl_xor(pd, off);
            ps += __shfl_xor(ps, off);
        }
        if (td == 0) {
            a_dst_arr[node] = pd;
            a_src_arr[node] = ps;
        }
    }
}

// ---------------------------------------------------------------------------
// K2: dst histogram (4 edges/thread, vectorized load).
// ---------------------------------------------------------------------------
__global__ __launch_bounds__(256) void gat_hist(
    const int* __restrict__ dst, int* __restrict__ cnt, int E)
{
    int base = (int)(blockIdx.x * blockDim.x + threadIdx.x) * 4;
    if (base + 4 <= E) {
        int4 d4 = *(const int4*)&dst[base];
        atomicAdd(&cnt[d4.x], 1);
        atomicAdd(&cnt[d4.y], 1);
        atomicAdd(&cnt[d4.z], 1);
        atomicAdd(&cnt[d4.w], 1);
    } else {
        for (int e = base; e < E; e++) atomicAdd(&cnt[dst[e]], 1);
    }
}

// ---------------------------------------------------------------------------
// K3: hierarchical exclusive scan cnt -> offs (+cursor).
// ---------------------------------------------------------------------------
__global__ __launch_bounds__(256) void gat_scan1(
    const int* __restrict__ cnt, int* __restrict__ bsum, int N)
{
    __shared__ int partial[256];
    int t = threadIdx.x;
    int base = blockIdx.x * SCAN_CHUNK + t * 4;
    int s = 0;
    #pragma unroll
    for (int i = 0; i < 4; i++) {
        int idx = base + i;
        if (idx < N) s += cnt[idx];
    }
    partial[t] = s;
    __syncthreads();
    for (int off = 128; off > 0; off >>= 1) {
        if (t < off) partial[t] += partial[t + off];
        __syncthreads();
    }
    if (t == 0) bsum[blockIdx.x] = partial[0];
}

__global__ __launch_bounds__(1024) void gat_scan2(
    const int* __restrict__ bsum, int* __restrict__ bbase,
    int* __restrict__ offs, int nb, int N)
{
    __shared__ int buf[1024];
    int t = threadIdx.x;
    int v = (t < nb) ? bsum[t] : 0;
    buf[t] = v;
    __syncthreads();
    for (int off = 1; off < 1024; off <<= 1) {
        int add = (t >= off) ? buf[t - off] : 0;
        __syncthreads();
        buf[t] += add;
        __syncthreads();
    }
    if (t < nb) bbase[t] = buf[t] - v;
    if (t == nb - 1) offs[N] = buf[t];
}

__global__ __launch_bounds__(256) void gat_scan3(
    const int* __restrict__ cnt, const int* __restrict__ bbase,
    int* __restrict__ offs, int* __restrict__ cursor, int N)
{
    __shared__ int partial[256];
    int t = threadIdx.x;
    int base = blockIdx.x * SCAN_CHUNK + t * 4;
    int c[4];
    int s = 0;
    #pragma unroll
    for (int i = 0; i < 4; i++) {
        int idx = base + i;
        c[i] = (idx < N) ? cnt[idx] : 0;
        s += c[i];
    }
    partial[t] = s;
    __syncthreads();
    for (int off = 1; off < 256; off <<= 1) {
        int add = (t >= off) ? partial[t - off] : 0;
        __syncthreads();
        partial[t] += add;
        __syncthreads();
    }
    int run = bbase[blockIdx.x] + partial[t] - s;
    #pragma unroll
    for (int i = 0; i < 4; i++) {
        int idx = base + i;
        if (idx < N) {
            offs[idx] = run;
            cursor[idx] = run;
            run += c[i];
        }
    }
}

// ---------------------------------------------------------------------------
// K4: CSR scatter. ONE packed 4 B record per edge: lo16 = src (N < 65536),
// hi16 = fp16(exp(leaky(logit))). Halves random-store line dirties vs 2 arrays.
// ---------------------------------------------------------------------------
__global__ __launch_bounds__(256) void gat_scatter(
    const int* __restrict__ src, const int* __restrict__ dst,
    const float* __restrict__ a_dst_arr, const float* __restrict__ a_src_arr,
    const float* __restrict__ Ab,
    int* __restrict__ cursor, uint_t* __restrict__ csr, int E)
{
    int e = (int)(blockIdx.x * blockDim.x + threadIdx.x);
    if (e >= E) return;
    int s = src[e];
    int t = dst[e];
    float v = a_dst_arr[t] + a_src_arr[s] + Ab[0];
    v = (v > 0.0f) ? v : 0.2f * v;
    float x = __expf(v);
    uint_t hb = (uint_t)__half_as_ushort(__float2half(x));
    uint_t rec = (hb << 16) | (uint_t)(s & 0xffff);
    int pos = atomicAdd(&cursor[t], 1);
    csr[pos] = rec;
}

// ---------------------------------------------------------------------------
// K5: gather-aggregate. One wave per dst node; lane = dim. 4-edge unroll keeps
// 4 independent Wh gathers in flight. wsum (denominator) is lane-redundant.
// ---------------------------------------------------------------------------
__global__ __launch_bounds__(256) void gat_agg(
    const int* __restrict__ offs, const uint_t* __restrict__ csr,
    const ushort_t* __restrict__ Whb, float* __restrict__ out, int N)
{
    int node = (int)((blockIdx.x * blockDim.x + threadIdx.x) >> 6);
    int lane = threadIdx.x & 63;
    if (node >= N) return;
    int u   = __builtin_amdgcn_readfirstlane(node);
    int beg = offs[u];
    int end = offs[u + 1];
    float acc = 0.0f, wsum = 0.0f;

    int j = beg;
    for (; j + 4 <= end; j += 4) {
        int4 r4 = *(const int4*)&csr[j];
        uint_t r0 = (uint_t)r4.x, r1 = (uint_t)r4.y, r2 = (uint_t)r4.z, r3 = (uint_t)r4.w;
        int s0 = (int)(r0 & 0xffffu), s1 = (int)(r1 & 0xffffu);
        int s2 = (int)(r2 & 0xffffu), s3 = (int)(r3 & 0xffffu);
        float f0 = bf16_to_f(Whb[(size_t)s0 * OUT_DIM + lane]);
        float f1 = bf16_to_f(Whb[(size_t)s1 * OUT_DIM + lane]);
        float f2 = bf16_to_f(Whb[(size_t)s2 * OUT_DIM + lane]);
        float f3 = bf16_to_f(Whb[(size_t)s3 * OUT_DIM + lane]);
        float w0 = __half2float(__ushort_as_half((ushort_t)(r0 >> 16)));
        float w1 = __half2float(__ushort_as_half((ushort_t)(r1 >> 16)));
        float w2 = __half2float(__ushort_as_half((ushort_t)(r2 >> 16)));
        float w3 = __half2float(__ushort_as_half((ushort_t)(r3 >> 16)));
        wsum += (w0 + w1) + (w2 + w3);
        acc = fmaf(w0, f0, acc);
        acc = fmaf(w1, f1, acc);
        acc = fmaf(w2, f2, acc);
        acc = fmaf(w3, f3, acc);
    }
    for (; j < end; j++) {
        uint_t r = csr[j];
        int s = (int)(r & 0xffffu);
        float w = __half2float(__ushort_as_half((ushort_t)(r >> 16)));
        wsum += w;
        acc = fmaf(w, bf16_to_f(Whb[(size_t)s * OUT_DIM + lane]), acc);
    }
    float inv = (end > beg) ? 1.0f / wsum : 0.0f;
    out[(size_t)u * OUT_DIM + lane] = acc * inv;
}

extern "C" void kernel_launch(void* const* d_in, const int* in_sizes, int n_in,
                              void* d_out, int out_size, void* d_ws, size_t ws_size,
                              hipStream_t stream)
{
    const float* h   = (const float*)d_in[0];
    const float* W_w = (const float*)d_in[1];
    const float* W_b = (const float*)d_in[2];
    const float* A_w = (const float*)d_in[3];
    const float* A_b = (const float*)d_in[4];
    const int*   src = (const int*)d_in[5];
    const int*   dst = (const int*)d_in[6];
    float* out = (float*)d_out;

    const int N = in_sizes[0] / IN_DIM;   // 50000
    const int E = in_sizes[5];            // 800000
    const int nb = (N + SCAN_CHUNK - 1) / SCAN_CHUNK;

    // Workspace: Whb[N*64 u16] | a_dst[N] | a_src[N] | cnt[N] | offs[N+1]
    //            | cursor[N] | bsum[nb] | bbase[nb] | csr[E u32]
    ushort_t* Whb   = (ushort_t*)d_ws;
    float* a_dst_a  = (float*)(Whb + (size_t)N * OUT_DIM);
    float* a_src_a  = a_dst_a + N;
    int*   cnt      = (int*)(a_src_a + N);
    int*   offs     = cnt + N;
    int*   cursor   = offs + (N + 1);
    int*   bsum     = cursor + N;
    int*   bbase    = bsum + nb;
    uint_t* csr     = (uint_t*)(bbase + nb);

    (void)hipMemsetAsync(cnt, 0, (size_t)N * sizeof(int), stream);

    {   // K1: projection
        int grid = (N + PROJ_NODES - 1) / PROJ_NODES;
        gat_proj<<<grid, 128, 0, stream>>>(h, W_w, W_b, A_w, Whb, a_dst_a, a_src_a, N);
    }
    {   // K2: histogram
        int grid = (E + 1023) / 1024;
        gat_hist<<<grid, 256, 0, stream>>>(dst, cnt, E);
    }
    // K3: scan
    gat_scan1<<<nb, 256, 0, stream>>>(cnt, bsum, N);
    gat_scan2<<<1, 1024, 0, stream>>>(bsum, bbase, offs, nb, N);
    gat_scan3<<<nb, 256, 0, stream>>>(cnt, bbase, offs, cursor, N);
    {   // K4: scatter
        int grid = (E + 255) / 256;
        gat_scatter<<<grid, 256, 0, stream>>>(src, dst, a_dst_a, a_src_a, A_b, cursor, csr, E);
    }
    {   // K5: gather-aggregate
        int grid = (N + 3) / 4;
        gat_agg<<<grid, 256, 0, stream>>>(offs, csr, Whb, out, N);
    }
}

// Round 6
// 201.808 us; speedup vs baseline: 1.9969x; 1.1079x over previous
//
#include <hip/hip_runtime.h>
#include <hip/hip_bf16.h>
#include <hip/hip_fp16.h>

#define IN_DIM 128
#define OUT_DIM 64
#define SCAN_CHUNK 1024

typedef __attribute__((ext_vector_type(8))) short short8v;   // 8 bf16 (4 VGPRs)
typedef __attribute__((ext_vector_type(4))) float float4v;   // MFMA acc
typedef unsigned short ushort_t;
typedef unsigned int uint_t;

__device__ inline float bf16_to_f(ushort_t u) {
    return __uint_as_float(((uint_t)u) << 16);
}
__device__ inline ushort_t f_to_bf16(float f) {
    uint_t x = __float_as_uint(f);
    uint_t r = (x + 0x7fffu + ((x >> 16) & 1u)) >> 16;   // RNE
    return (ushort_t)r;
}

// ---------------------------------------------------------------------------
// K1: projection via MFMA. One wave = 16 nodes x 64 dims, K=128 in 4 steps of
// 16x16x32 bf16 MFMA (4 dim-blocks). A-frag: h rows converted fp32->bf16 on
// the fly from global. B-frag: W pre-swizzled to fragment layout in LDS (16 KB)
// once per block. Epilogue adds bias, stores Whb (bf16) and the two attention
// partials (fp32 accs, reduced across the 16 col-lanes).
// Layouts (guide §3, m89-verified): A[m=lane&15][k=quad*8+j],
// B[k=quad*8+j][n=lane&15], C/D col=lane&15, row=quad*4+reg.
// ---------------------------------------------------------------------------
__global__ __launch_bounds__(256) void gat_proj(
    const float* __restrict__ h, const float* __restrict__ W,
    const float* __restrict__ Wb, const float* __restrict__ Aw,
    ushort_t* __restrict__ Whb, float* __restrict__ a_dst_arr,
    float* __restrict__ a_src_arr, int N)
{
    __shared__ ushort_t Wl[16 * 64 * 8];   // 16 frags x 64 lanes x 8 bf16 = 16 KB

    const int t = threadIdx.x;

    // Stage W swizzled: frag = kb*4+db; entry (frag,lane,j) = W[kb*32+quad*8+j][db*16+col]
    {
        int f = t * 32;
        #pragma unroll
        for (int i = 0; i < 32; i++, f++) {
            int frag = f >> 9;
            int lane = (f >> 3) & 63;
            int j    = f & 7;
            int k    = (frag >> 2) * 32 + (lane >> 4) * 8 + j;
            int d    = (frag & 3) * 16 + (lane & 15);
            Wl[f] = f_to_bf16(W[k * OUT_DIM + d]);
        }
    }
    __syncthreads();

    const int wave  = t >> 6;
    const int lane  = t & 63;
    const int node0 = (blockIdx.x * 4 + wave) * 16;
    if (node0 >= N) return;
    const int quad = lane >> 4;
    const int col  = lane & 15;

    const int rowc = min(node0 + col, N - 1);   // clamp for ragged tail
    const float* __restrict__ arow = h + (size_t)rowc * IN_DIM;

    float4v acc[4];
    #pragma unroll
    for (int db = 0; db < 4; db++) acc[db] = (float4v){0.f, 0.f, 0.f, 0.f};

    #pragma unroll
    for (int kb = 0; kb < 4; kb++) {
        const float* ap = arow + kb * 32 + quad * 8;
        float4 a0 = *(const float4*)ap;
        float4 a1 = *(const float4*)(ap + 4);
        union { short8v v; ushort_t u[8]; } af;
        af.u[0] = f_to_bf16(a0.x); af.u[1] = f_to_bf16(a0.y);
        af.u[2] = f_to_bf16(a0.z); af.u[3] = f_to_bf16(a0.w);
        af.u[4] = f_to_bf16(a1.x); af.u[5] = f_to_bf16(a1.y);
        af.u[6] = f_to_bf16(a1.z); af.u[7] = f_to_bf16(a1.w);
        #pragma unroll
        for (int db = 0; db < 4; db++) {
            short8v bf = *(const short8v*)&Wl[(((kb << 2) | db) * 64 + lane) * 8];
            acc[db] = __builtin_amdgcn_mfma_f32_16x16x32_bf16(af.v, bf, acc[db], 0, 0, 0);
        }
    }

    // Per-lane epilogue constants for this col.
    float wbv[4], awd[4], aws[4];
    #pragma unroll
    for (int db = 0; db < 4; db++) {
        wbv[db] = Wb[db * 16 + col];
        awd[db] = Aw[db * 16 + col];
        aws[db] = Aw[OUT_DIM + db * 16 + col];
    }

    float pd[4] = {0.f, 0.f, 0.f, 0.f};
    float ps[4] = {0.f, 0.f, 0.f, 0.f};
    #pragma unroll
    for (int db = 0; db < 4; db++) {
        #pragma unroll
        for (int r = 0; r < 4; r++) {
            float v = acc[db][r] + wbv[db];
            int node = node0 + quad * 4 + r;
            if (node < N)
                Whb[(size_t)node * OUT_DIM + db * 16 + col] = f_to_bf16(v);
            pd[r] = fmaf(v, awd[db], pd[r]);
            ps[r] = fmaf(v, aws[db], ps[r]);
        }
    }
    #pragma unroll
    for (int r = 0; r < 4; r++) {
        float d_ = pd[r], s_ = ps[r];
        #pragma unroll
        for (int off = 1; off < 16; off <<= 1) {
            d_ += __shfl_xor(d_, off);
            s_ += __shfl_xor(s_, off);
        }
        int node = node0 + quad * 4 + r;
        if (col == 0 && node < N) {
            a_dst_arr[node] = d_;
            a_src_arr[node] = s_;
        }
    }
}

// ---------------------------------------------------------------------------
// K2: dst histogram (4 edges/thread, vectorized load).
// ---------------------------------------------------------------------------
__global__ __launch_bounds__(256) void gat_hist(
    const int* __restrict__ dst, int* __restrict__ cnt, int E)
{
    int base = (int)(blockIdx.x * blockDim.x + threadIdx.x) * 4;
    if (base + 4 <= E) {
        int4 d4 = *(const int4*)&dst[base];
        atomicAdd(&cnt[d4.x], 1);
        atomicAdd(&cnt[d4.y], 1);
        atomicAdd(&cnt[d4.z], 1);
        atomicAdd(&cnt[d4.w], 1);
    } else {
        for (int e = base; e < E; e++) atomicAdd(&cnt[dst[e]], 1);
    }
}

// ---------------------------------------------------------------------------
// K3: hierarchical exclusive scan cnt -> offs (+cursor).
// ---------------------------------------------------------------------------
__global__ __launch_bounds__(256) void gat_scan1(
    const int* __restrict__ cnt, int* __restrict__ bsum, int N)
{
    __shared__ int partial[256];
    int t = threadIdx.x;
    int base = blockIdx.x * SCAN_CHUNK + t * 4;
    int s = 0;
    #pragma unroll
    for (int i = 0; i < 4; i++) {
        int idx = base + i;
        if (idx < N) s += cnt[idx];
    }
    partial[t] = s;
    __syncthreads();
    for (int off = 128; off > 0; off >>= 1) {
        if (t < off) partial[t] += partial[t + off];
        __syncthreads();
    }
    if (t == 0) bsum[blockIdx.x] = partial[0];
}

__global__ __launch_bounds__(1024) void gat_scan2(
    const int* __restrict__ bsum, int* __restrict__ bbase,
    int* __restrict__ offs, int nb, int N)
{
    __shared__ int buf[1024];
    int t = threadIdx.x;
    int v = (t < nb) ? bsum[t] : 0;
    buf[t] = v;
    __syncthreads();
    for (int off = 1; off < 1024; off <<= 1) {
        int add = (t >= off) ? buf[t - off] : 0;
        __syncthreads();
        buf[t] += add;
        __syncthreads();
    }
    if (t < nb) bbase[t] = buf[t] - v;
    if (t == nb - 1) offs[N] = buf[t];
}

__global__ __launch_bounds__(256) void gat_scan3(
    const int* __restrict__ cnt, const int* __restrict__ bbase,
    int* __restrict__ offs, int* __restrict__ cursor, int N)
{
    __shared__ int partial[256];
    int t = threadIdx.x;
    int base = blockIdx.x * SCAN_CHUNK + t * 4;
    int c[4];
    int s = 0;
    #pragma unroll
    for (int i = 0; i < 4; i++) {
        int idx = base + i;
        c[i] = (idx < N) ? cnt[idx] : 0;
        s += c[i];
    }
    partial[t] = s;
    __syncthreads();
    for (int off = 1; off < 256; off <<= 1) {
        int add = (t >= off) ? partial[t - off] : 0;
        __syncthreads();
        partial[t] += add;
        __syncthreads();
    }
    int run = bbase[blockIdx.x] + partial[t] - s;
    #pragma unroll
    for (int i = 0; i < 4; i++) {
        int idx = base + i;
        if (idx < N) {
            offs[idx] = run;
            cursor[idx] = run;
            run += c[i];
        }
    }
}

// ---------------------------------------------------------------------------
// K4: CSR scatter, 2 edges/thread (independent atomic chains for MLP=2).
// Record: lo16 = src, hi16 = fp16(exp(leaky(logit))).
// ---------------------------------------------------------------------------
__global__ __launch_bounds__(256) void gat_scatter(
    const int* __restrict__ src, const int* __restrict__ dst,
    const float* __restrict__ a_dst_arr, const float* __restrict__ a_src_arr,
    const float* __restrict__ Ab,
    int* __restrict__ cursor, uint_t* __restrict__ csr, int E)
{
    int e0 = (int)(blockIdx.x * blockDim.x + threadIdx.x) * 2;
    if (e0 + 2 <= E) {
        int2 s2 = *(const int2*)&src[e0];
        int2 t2 = *(const int2*)&dst[e0];
        float ad0 = a_dst_arr[t2.x], ad1 = a_dst_arr[t2.y];
        float as0 = a_src_arr[s2.x], as1 = a_src_arr[s2.y];
        float ab = Ab[0];
        float v0 = ad0 + as0 + ab;
        float v1 = ad1 + as1 + ab;
        v0 = (v0 > 0.0f) ? v0 : 0.2f * v0;
        v1 = (v1 > 0.0f) ? v1 : 0.2f * v1;
        float x0 = __expf(v0), x1 = __expf(v1);
        uint_t r0 = (((uint_t)__half_as_ushort(__float2half(x0))) << 16) | (uint_t)(s2.x & 0xffff);
        uint_t r1 = (((uint_t)__half_as_ushort(__float2half(x1))) << 16) | (uint_t)(s2.y & 0xffff);
        int p0 = atomicAdd(&cursor[t2.x], 1);
        int p1 = atomicAdd(&cursor[t2.y], 1);
        csr[p0] = r0;
        csr[p1] = r1;
    } else {
        for (int e = e0; e < E; e++) {
            int s = src[e];
            int t = dst[e];
            float v = a_dst_arr[t] + a_src_arr[s] + Ab[0];
            v = (v > 0.0f) ? v : 0.2f * v;
            float x = __expf(v);
            uint_t rec = (((uint_t)__half_as_ushort(__float2half(x))) << 16) | (uint_t)(s & 0xffff);
            int pos = atomicAdd(&cursor[t], 1);
            csr[pos] = rec;
        }
    }
}

// ---------------------------------------------------------------------------
// K5: gather-aggregate. One wave per dst node; lane = dim. 4-edge unroll.
// ---------------------------------------------------------------------------
__global__ __launch_bounds__(256) void gat_agg(
    const int* __restrict__ offs, const uint_t* __restrict__ csr,
    const ushort_t* __restrict__ Whb, float* __restrict__ out, int N)
{
    int node = (int)((blockIdx.x * blockDim.x + threadIdx.x) >> 6);
    int lane = threadIdx.x & 63;
    if (node >= N) return;
    int u   = __builtin_amdgcn_readfirstlane(node);
    int beg = offs[u];
    int end = offs[u + 1];
    float acc = 0.0f, wsum = 0.0f;

    int j = beg;
    for (; j + 4 <= end; j += 4) {
        int4 r4 = *(const int4*)&csr[j];
        uint_t r0 = (uint_t)r4.x, r1 = (uint_t)r4.y, r2 = (uint_t)r4.z, r3 = (uint_t)r4.w;
        int s0 = (int)(r0 & 0xffffu), s1 = (int)(r1 & 0xffffu);
        int s2 = (int)(r2 & 0xffffu), s3 = (int)(r3 & 0xffffu);
        float f0 = bf16_to_f(Whb[(size_t)s0 * OUT_DIM + lane]);
        float f1 = bf16_to_f(Whb[(size_t)s1 * OUT_DIM + lane]);
        float f2 = bf16_to_f(Whb[(size_t)s2 * OUT_DIM + lane]);
        float f3 = bf16_to_f(Whb[(size_t)s3 * OUT_DIM + lane]);
        float w0 = __half2float(__ushort_as_half((ushort_t)(r0 >> 16)));
        float w1 = __half2float(__ushort_as_half((ushort_t)(r1 >> 16)));
        float w2 = __half2float(__ushort_as_half((ushort_t)(r2 >> 16)));
        float w3 = __half2float(__ushort_as_half((ushort_t)(r3 >> 16)));
        wsum += (w0 + w1) + (w2 + w3);
        acc = fmaf(w0, f0, acc);
        acc = fmaf(w1, f1, acc);
        acc = fmaf(w2, f2, acc);
        acc = fmaf(w3, f3, acc);
    }
    for (; j < end; j++) {
        uint_t r = csr[j];
        int s = (int)(r & 0xffffu);
        float w = __half2float(__ushort_as_half((ushort_t)(r >> 16)));
        wsum += w;
        acc = fmaf(w, bf16_to_f(Whb[(size_t)s * OUT_DIM + lane]), acc);
    }
    float inv = (end > beg) ? 1.0f / wsum : 0.0f;
    out[(size_t)u * OUT_DIM + lane] = acc * inv;
}

extern "C" void kernel_launch(void* const* d_in, const int* in_sizes, int n_in,
                              void* d_out, int out_size, void* d_ws, size_t ws_size,
                              hipStream_t stream)
{
    const float* h   = (const float*)d_in[0];
    const float* W_w = (const float*)d_in[1];
    const float* W_b = (const float*)d_in[2];
    const float* A_w = (const float*)d_in[3];
    const float* A_b = (const float*)d_in[4];
    const int*   src = (const int*)d_in[5];
    const int*   dst = (const int*)d_in[6];
    float* out = (float*)d_out;

    const int N = in_sizes[0] / IN_DIM;   // 50000
    const int E = in_sizes[5];            // 800000
    const int nb = (N + SCAN_CHUNK - 1) / SCAN_CHUNK;

    // Workspace: Whb[N*64 u16] | a_dst[N] | a_src[N] | cnt[N] | offs[N+1]
    //            | cursor[N] | bsum[nb] | bbase[nb] | csr[E u32]
    ushort_t* Whb   = (ushort_t*)d_ws;
    float* a_dst_a  = (float*)(Whb + (size_t)N * OUT_DIM);
    float* a_src_a  = a_dst_a + N;
    int*   cnt      = (int*)(a_src_a + N);
    int*   offs     = cnt + N;
    int*   cursor   = offs + (N + 1);
    int*   bsum     = cursor + N;
    int*   bbase    = bsum + nb;
    uint_t* csr     = (uint_t*)(bbase + nb);

    (void)hipMemsetAsync(cnt, 0, (size_t)N * sizeof(int), stream);

    {   // K1: projection (MFMA): 16 nodes/wave, 4 waves/block
        int waves = (N + 15) / 16;
        int grid  = (waves + 3) / 4;
        gat_proj<<<grid, 256, 0, stream>>>(h, W_w, W_b, A_w, Whb, a_dst_a, a_src_a, N);
    }
    {   // K2: histogram
        int grid = (E + 1023) / 1024;
        gat_hist<<<grid, 256, 0, stream>>>(dst, cnt, E);
    }
    // K3: scan
    gat_scan1<<<nb, 256, 0, stream>>>(cnt, bsum, N);
    gat_scan2<<<1, 1024, 0, stream>>>(bsum, bbase, offs, nb, N);
    gat_scan3<<<nb, 256, 0, stream>>>(cnt, bbase, offs, cursor, N);
    {   // K4: scatter (2 edges/thread)
        int grid = (E / 2 + 255) / 256;
        gat_scatter<<<grid, 256, 0, stream>>>(src, dst, a_dst_a, a_src_a, A_b, cursor, csr, E);
    }
    {   // K5: gather-aggregate
        int grid = (N + 3) / 4;
        gat_agg<<<grid, 256, 0, stream>>>(offs, csr, Whb, out, N);
    }
}

// Round 7
// 179.907 us; speedup vs baseline: 2.2400x; 1.1217x over previous
//
#include <hip/hip_runtime.h>
#include <hip/hip_bf16.h>
#include <hip/hip_fp16.h>

#define IN_DIM 128
#define OUT_DIM 64
#define SCAN_CHUNK 1024

typedef __attribute__((ext_vector_type(8))) short short8v;   // 8 bf16 (4 VGPRs)
typedef __attribute__((ext_vector_type(4))) float float4v;   // MFMA acc
typedef unsigned short ushort_t;
typedef unsigned int uint_t;

__device__ inline float bf16_to_f(ushort_t u) {
    return __uint_as_float(((uint_t)u) << 16);
}
__device__ inline ushort_t f_to_bf16(float f) {
    uint_t x = __float_as_uint(f);
    uint_t r = (x + 0x7fffu + ((x >> 16) & 1u)) >> 16;   // RNE
    return (ushort_t)r;
}

// ---------------------------------------------------------------------------
// K1: projection via MFMA. One wave = 16 nodes x 64 dims, K=128 in 4 steps of
// 16x16x32 bf16 MFMA (4 dim-blocks). B-frag: W pre-swizzled in LDS (16 KB).
// Epilogue adds bias, stores Whb (bf16) + attention partials.
// Layouts (m89-verified): A[m=lane&15][k=quad*8+j], B[k=quad*8+j][n=lane&15],
// C/D col=lane&15, row=quad*4+reg.
// ---------------------------------------------------------------------------
__global__ __launch_bounds__(256) void gat_proj(
    const float* __restrict__ h, const float* __restrict__ W,
    const float* __restrict__ Wb, const float* __restrict__ Aw,
    ushort_t* __restrict__ Whb, float* __restrict__ a_dst_arr,
    float* __restrict__ a_src_arr, int N)
{
    __shared__ ushort_t Wl[16 * 64 * 8];   // 16 KB

    const int t = threadIdx.x;
    {
        int f = t * 32;
        #pragma unroll
        for (int i = 0; i < 32; i++, f++) {
            int frag = f >> 9;
            int lane = (f >> 3) & 63;
            int j    = f & 7;
            int k    = (frag >> 2) * 32 + (lane >> 4) * 8 + j;
            int d    = (frag & 3) * 16 + (lane & 15);
            Wl[f] = f_to_bf16(W[k * OUT_DIM + d]);
        }
    }
    __syncthreads();

    const int wave  = t >> 6;
    const int lane  = t & 63;
    const int node0 = (blockIdx.x * 4 + wave) * 16;
    if (node0 >= N) return;
    const int quad = lane >> 4;
    const int col  = lane & 15;

    const int rowc = min(node0 + col, N - 1);   // clamp for ragged tail
    const float* __restrict__ arow = h + (size_t)rowc * IN_DIM;

    float4v acc[4];
    #pragma unroll
    for (int db = 0; db < 4; db++) acc[db] = (float4v){0.f, 0.f, 0.f, 0.f};

    #pragma unroll
    for (int kb = 0; kb < 4; kb++) {
        const float* ap = arow + kb * 32 + quad * 8;
        float4 a0 = *(const float4*)ap;
        float4 a1 = *(const float4*)(ap + 4);
        union { short8v v; ushort_t u[8]; } af;
        af.u[0] = f_to_bf16(a0.x); af.u[1] = f_to_bf16(a0.y);
        af.u[2] = f_to_bf16(a0.z); af.u[3] = f_to_bf16(a0.w);
        af.u[4] = f_to_bf16(a1.x); af.u[5] = f_to_bf16(a1.y);
        af.u[6] = f_to_bf16(a1.z); af.u[7] = f_to_bf16(a1.w);
        #pragma unroll
        for (int db = 0; db < 4; db++) {
            short8v bf = *(const short8v*)&Wl[(((kb << 2) | db) * 64 + lane) * 8];
            acc[db] = __builtin_amdgcn_mfma_f32_16x16x32_bf16(af.v, bf, acc[db], 0, 0, 0);
        }
    }

    float wbv[4], awd[4], aws[4];
    #pragma unroll
    for (int db = 0; db < 4; db++) {
        wbv[db] = Wb[db * 16 + col];
        awd[db] = Aw[db * 16 + col];
        aws[db] = Aw[OUT_DIM + db * 16 + col];
    }

    float pd[4] = {0.f, 0.f, 0.f, 0.f};
    float ps[4] = {0.f, 0.f, 0.f, 0.f};
    #pragma unroll
    for (int db = 0; db < 4; db++) {
        #pragma unroll
        for (int r = 0; r < 4; r++) {
            float v = acc[db][r] + wbv[db];
            int node = node0 + quad * 4 + r;
            if (node < N)
                Whb[(size_t)node * OUT_DIM + db * 16 + col] = f_to_bf16(v);
            pd[r] = fmaf(v, awd[db], pd[r]);
            ps[r] = fmaf(v, aws[db], ps[r]);
        }
    }
    #pragma unroll
    for (int r = 0; r < 4; r++) {
        float d_ = pd[r], s_ = ps[r];
        #pragma unroll
        for (int off = 1; off < 16; off <<= 1) {
            d_ += __shfl_xor(d_, off);
            s_ += __shfl_xor(s_, off);
        }
        int node = node0 + quad * 4 + r;
        if (col == 0 && node < N) {
            a_dst_arr[node] = d_;
            a_src_arr[node] = s_;
        }
    }
}

// ---------------------------------------------------------------------------
// K2: dst histogram + per-edge rank (atomicAdd return). 4 edges/thread.
// rank write is coalesced; ranks are unique within each dst segment.
// ---------------------------------------------------------------------------
__global__ __launch_bounds__(256) void gat_hist_rank(
    const int* __restrict__ dst, int* __restrict__ cnt,
    int* __restrict__ rank, int E)
{
    int base = (int)(blockIdx.x * blockDim.x + threadIdx.x) * 4;
    if (base + 4 <= E) {
        int4 d4 = *(const int4*)&dst[base];
        int r0 = atomicAdd(&cnt[d4.x], 1);
        int r1 = atomicAdd(&cnt[d4.y], 1);
        int r2 = atomicAdd(&cnt[d4.z], 1);
        int r3 = atomicAdd(&cnt[d4.w], 1);
        *(int4*)&rank[base] = make_int4(r0, r1, r2, r3);
    } else {
        for (int e = base; e < E; e++) rank[e] = atomicAdd(&cnt[dst[e]], 1);
    }
}

// ---------------------------------------------------------------------------
// K3: hierarchical exclusive scan cnt -> offs.
// ---------------------------------------------------------------------------
__global__ __launch_bounds__(256) void gat_scan1(
    const int* __restrict__ cnt, int* __restrict__ bsum, int N)
{
    __shared__ int partial[256];
    int t = threadIdx.x;
    int base = blockIdx.x * SCAN_CHUNK + t * 4;
    int s = 0;
    #pragma unroll
    for (int i = 0; i < 4; i++) {
        int idx = base + i;
        if (idx < N) s += cnt[idx];
    }
    partial[t] = s;
    __syncthreads();
    for (int off = 128; off > 0; off >>= 1) {
        if (t < off) partial[t] += partial[t + off];
        __syncthreads();
    }
    if (t == 0) bsum[blockIdx.x] = partial[0];
}

__global__ __launch_bounds__(1024) void gat_scan2(
    const int* __restrict__ bsum, int* __restrict__ bbase,
    int* __restrict__ offs, int nb, int N)
{
    __shared__ int buf[1024];
    int t = threadIdx.x;
    int v = (t < nb) ? bsum[t] : 0;
    buf[t] = v;
    __syncthreads();
    for (int off = 1; off < 1024; off <<= 1) {
        int add = (t >= off) ? buf[t - off] : 0;
        __syncthreads();
        buf[t] += add;
        __syncthreads();
    }
    if (t < nb) bbase[t] = buf[t] - v;
    if (t == nb - 1) offs[N] = buf[t];
}

__global__ __launch_bounds__(256) void gat_scan3(
    const int* __restrict__ cnt, const int* __restrict__ bbase,
    int* __restrict__ offs, int N)
{
    __shared__ int partial[256];
    int t = threadIdx.x;
    int base = blockIdx.x * SCAN_CHUNK + t * 4;
    int c[4];
    int s = 0;
    #pragma unroll
    for (int i = 0; i < 4; i++) {
        int idx = base + i;
        c[i] = (idx < N) ? cnt[idx] : 0;
        s += c[i];
    }
    partial[t] = s;
    __syncthreads();
    for (int off = 1; off < 256; off <<= 1) {
        int add = (t >= off) ? partial[t - off] : 0;
        __syncthreads();
        partial[t] += add;
        __syncthreads();
    }
    int run = bbase[blockIdx.x] + partial[t] - s;
    #pragma unroll
    for (int i = 0; i < 4; i++) {
        int idx = base + i;
        if (idx < N) {
            offs[idx] = run;
            run += c[i];
        }
    }
}

// ---------------------------------------------------------------------------
// K4: CSR scatter — NO atomics. pos = offs[dst] + rank[e]; fire-and-forget
// random 4 B stores (4 independent per thread).
// Record: lo16 = src, hi16 = fp16(exp(leaky(logit))).
// ---------------------------------------------------------------------------
__global__ __launch_bounds__(256) void gat_scatter(
    const int* __restrict__ src, const int* __restrict__ dst,
    const int* __restrict__ rank, const int* __restrict__ offs,
    const float* __restrict__ a_dst_arr, const float* __restrict__ a_src_arr,
    const float* __restrict__ Ab,
    uint_t* __restrict__ csr, int E)
{
    int base = (int)(blockIdx.x * blockDim.x + threadIdx.x) * 4;
    float ab = Ab[0];
    if (base + 4 <= E) {
        int4 s4 = *(const int4*)&src[base];
        int4 t4 = *(const int4*)&dst[base];
        int4 k4 = *(const int4*)&rank[base];
        int ss[4] = {s4.x, s4.y, s4.z, s4.w};
        int tt[4] = {t4.x, t4.y, t4.z, t4.w};
        int kk[4] = {k4.x, k4.y, k4.z, k4.w};
        #pragma unroll
        for (int i = 0; i < 4; i++) {
            float v = a_dst_arr[tt[i]] + a_src_arr[ss[i]] + ab;
            v = (v > 0.0f) ? v : 0.2f * v;
            float x = __expf(v);
            uint_t rec = (((uint_t)__half_as_ushort(__float2half(x))) << 16)
                       | (uint_t)(ss[i] & 0xffff);
            csr[offs[tt[i]] + kk[i]] = rec;
        }
    } else {
        for (int e = base; e < E; e++) {
            int s = src[e];
            int t = dst[e];
            float v = a_dst_arr[t] + a_src_arr[s] + ab;
            v = (v > 0.0f) ? v : 0.2f * v;
            float x = __expf(v);
            uint_t rec = (((uint_t)__half_as_ushort(__float2half(x))) << 16)
                       | (uint_t)(s & 0xffff);
            csr[offs[t] + rank[e]] = rec;
        }
    }
}

// ---------------------------------------------------------------------------
// K5: gather-aggregate. One wave per dst node; lane = dim. 4-edge unroll.
// ---------------------------------------------------------------------------
__global__ __launch_bounds__(256) void gat_agg(
    const int* __restrict__ offs, const uint_t* __restrict__ csr,
    const ushort_t* __restrict__ Whb, float* __restrict__ out, int N)
{
    int node = (int)((blockIdx.x * blockDim.x + threadIdx.x) >> 6);
    int lane = threadIdx.x & 63;
    if (node >= N) return;
    int u   = __builtin_amdgcn_readfirstlane(node);
    int beg = offs[u];
    int end = offs[u + 1];
    float acc = 0.0f, wsum = 0.0f;

    int j = beg;
    for (; j + 4 <= end; j += 4) {
        int4 r4 = *(const int4*)&csr[j];
        uint_t r0 = (uint_t)r4.x, r1 = (uint_t)r4.y, r2 = (uint_t)r4.z, r3 = (uint_t)r4.w;
        int s0 = (int)(r0 & 0xffffu), s1 = (int)(r1 & 0xffffu);
        int s2 = (int)(r2 & 0xffffu), s3 = (int)(r3 & 0xffffu);
        float f0 = bf16_to_f(Whb[(size_t)s0 * OUT_DIM + lane]);
        float f1 = bf16_to_f(Whb[(size_t)s1 * OUT_DIM + lane]);
        float f2 = bf16_to_f(Whb[(size_t)s2 * OUT_DIM + lane]);
        float f3 = bf16_to_f(Whb[(size_t)s3 * OUT_DIM + lane]);
        float w0 = __half2float(__ushort_as_half((ushort_t)(r0 >> 16)));
        float w1 = __half2float(__ushort_as_half((ushort_t)(r1 >> 16)));
        float w2 = __half2float(__ushort_as_half((ushort_t)(r2 >> 16)));
        float w3 = __half2float(__ushort_as_half((ushort_t)(r3 >> 16)));
        wsum += (w0 + w1) + (w2 + w3);
        acc = fmaf(w0, f0, acc);
        acc = fmaf(w1, f1, acc);
        acc = fmaf(w2, f2, acc);
        acc = fmaf(w3, f3, acc);
    }
    for (; j < end; j++) {
        uint_t r = csr[j];
        int s = (int)(r & 0xffffu);
        float w = __half2float(__ushort_as_half((ushort_t)(r >> 16)));
        wsum += w;
        acc = fmaf(w, bf16_to_f(Whb[(size_t)s * OUT_DIM + lane]), acc);
    }
    float inv = (end > beg) ? 1.0f / wsum : 0.0f;
    out[(size_t)u * OUT_DIM + lane] = acc * inv;
}

extern "C" void kernel_launch(void* const* d_in, const int* in_sizes, int n_in,
                              void* d_out, int out_size, void* d_ws, size_t ws_size,
                              hipStream_t stream)
{
    const float* h   = (const float*)d_in[0];
    const float* W_w = (const float*)d_in[1];
    const float* W_b = (const float*)d_in[2];
    const float* A_w = (const float*)d_in[3];
    const float* A_b = (const float*)d_in[4];
    const int*   src = (const int*)d_in[5];
    const int*   dst = (const int*)d_in[6];
    float* out = (float*)d_out;

    const int N = in_sizes[0] / IN_DIM;   // 50000
    const int E = in_sizes[5];            // 800000
    const int nb = (N + SCAN_CHUNK - 1) / SCAN_CHUNK;

    // Workspace: Whb[N*64 u16] | a_dst[N] | a_src[N] | cnt[N] | offs[N+1]
    //            | bsum[nb] | bbase[nb] | rank[E] | csr[E u32]
    ushort_t* Whb   = (ushort_t*)d_ws;
    float* a_dst_a  = (float*)(Whb + (size_t)N * OUT_DIM);
    float* a_src_a  = a_dst_a + N;
    int*   cnt      = (int*)(a_src_a + N);
    int*   offs     = cnt + N;
    int*   bsum     = offs + (N + 1);
    int*   bbase    = bsum + nb;
    int*   rank     = bbase + nb;
    uint_t* csr     = (uint_t*)(rank + E);

    (void)hipMemsetAsync(cnt, 0, (size_t)N * sizeof(int), stream);

    {   // K1: projection (MFMA)
        int waves = (N + 15) / 16;
        int grid  = (waves + 3) / 4;
        gat_proj<<<grid, 256, 0, stream>>>(h, W_w, W_b, A_w, Whb, a_dst_a, a_src_a, N);
    }
    {   // K2: histogram + rank
        int grid = (E + 1023) / 1024;
        gat_hist_rank<<<grid, 256, 0, stream>>>(dst, cnt, rank, E);
    }
    // K3: scan
    gat_scan1<<<nb, 256, 0, stream>>>(cnt, bsum, N);
    gat_scan2<<<1, 1024, 0, stream>>>(bsum, bbase, offs, nb, N);
    gat_scan3<<<nb, 256, 0, stream>>>(cnt, bbase, offs, N);
    {   // K4: scatter (atomic-free, 4 edges/thread)
        int grid = (E + 1023) / 1024;
        gat_scatter<<<grid, 256, 0, stream>>>(src, dst, rank, offs, a_dst_a, a_src_a,
                                              A_b, csr, E);
    }
    {   // K5: gather-aggregate
        int grid = (N + 3) / 4;
        gat_agg<<<grid, 256, 0, stream>>>(offs, csr, Whb, out, N);
    }
}

// Round 8
// 165.202 us; speedup vs baseline: 2.4394x; 1.0890x over previous
//
#include <hip/hip_runtime.h>
#include <hip/hip_bf16.h>
#include <hip/hip_fp16.h>

#define IN_DIM 128
#define OUT_DIM 64
#define MAXDEG 128   // padded-CSR stride; deg is Poisson(16), P(>=128) ~ 1e-62

typedef __attribute__((ext_vector_type(8))) short short8v;   // 8 bf16 (4 VGPRs)
typedef __attribute__((ext_vector_type(4))) float float4v;   // MFMA acc
typedef unsigned short ushort_t;
typedef unsigned int uint_t;

__device__ inline float bf16_to_f(ushort_t u) {
    return __uint_as_float(((uint_t)u) << 16);
}
__device__ inline ushort_t f_to_bf16(float f) {
    uint_t x = __float_as_uint(f);
    uint_t r = (x + 0x7fffu + ((x >> 16) & 1u)) >> 16;   // RNE
    return (ushort_t)r;
}

// ---------------------------------------------------------------------------
// K1 (fused): blocks [0, HB) = dst histogram + per-edge rank (independent of
// proj); blocks [HB, HB+PB) = MFMA projection. Hist first: it is the longer
// pole, so it starts dispatching earliest.
//
// Proj: one wave = 16 nodes x 64 dims, K=128 in 4 steps of 16x16x32 bf16 MFMA.
// W pre-swizzled in LDS. Layouts (m89-verified): A[m=lane&15][k=quad*8+j],
// B[k=quad*8+j][n=lane&15], C/D col=lane&15, row=quad*4+reg.
// ---------------------------------------------------------------------------
__global__ __launch_bounds__(256) void gat_fused(
    const float* __restrict__ h, const float* __restrict__ W,
    const float* __restrict__ Wb, const float* __restrict__ Aw,
    ushort_t* __restrict__ Whb, float* __restrict__ a_dst_arr,
    float* __restrict__ a_src_arr, int N,
    const int* __restrict__ dst, int* __restrict__ cnt,
    int* __restrict__ rank, int E, int HB)
{
    __shared__ ushort_t Wl[16 * 64 * 8];   // 16 KB (proj blocks only)

    const int t = threadIdx.x;

    if ((int)blockIdx.x < HB) {
        // ---- histogram + rank (4 edges/thread; coalesced rank store) ----
        int base = ((int)blockIdx.x * 256 + t) * 4;
        if (base + 4 <= E) {
            int4 d4 = *(const int4*)&dst[base];
            int r0 = atomicAdd(&cnt[d4.x], 1);
            int r1 = atomicAdd(&cnt[d4.y], 1);
            int r2 = atomicAdd(&cnt[d4.z], 1);
            int r3 = atomicAdd(&cnt[d4.w], 1);
            *(int4*)&rank[base] = make_int4(r0, r1, r2, r3);
        } else {
            for (int e = base; e < E; e++) rank[e] = atomicAdd(&cnt[dst[e]], 1);
        }
        return;
    }

    // ---- projection ----
    const int pb = (int)blockIdx.x - HB;
    {
        int f = t * 32;
        #pragma unroll
        for (int i = 0; i < 32; i++, f++) {
            int frag = f >> 9;
            int lane = (f >> 3) & 63;
            int j    = f & 7;
            int k    = (frag >> 2) * 32 + (lane >> 4) * 8 + j;
            int d    = (frag & 3) * 16 + (lane & 15);
            Wl[f] = f_to_bf16(W[k * OUT_DIM + d]);
        }
    }
    __syncthreads();

    const int wave  = t >> 6;
    const int lane  = t & 63;
    const int node0 = (pb * 4 + wave) * 16;
    if (node0 >= N) return;
    const int quad = lane >> 4;
    const int col  = lane & 15;

    const int rowc = min(node0 + col, N - 1);   // clamp for ragged tail
    const float* __restrict__ arow = h + (size_t)rowc * IN_DIM;

    float4v acc[4];
    #pragma unroll
    for (int db = 0; db < 4; db++) acc[db] = (float4v){0.f, 0.f, 0.f, 0.f};

    #pragma unroll
    for (int kb = 0; kb < 4; kb++) {
        const float* ap = arow + kb * 32 + quad * 8;
        float4 a0 = *(const float4*)ap;
        float4 a1 = *(const float4*)(ap + 4);
        union { short8v v; ushort_t u[8]; } af;
        af.u[0] = f_to_bf16(a0.x); af.u[1] = f_to_bf16(a0.y);
        af.u[2] = f_to_bf16(a0.z); af.u[3] = f_to_bf16(a0.w);
        af.u[4] = f_to_bf16(a1.x); af.u[5] = f_to_bf16(a1.y);
        af.u[6] = f_to_bf16(a1.z); af.u[7] = f_to_bf16(a1.w);
        #pragma unroll
        for (int db = 0; db < 4; db++) {
            short8v bf = *(const short8v*)&Wl[(((kb << 2) | db) * 64 + lane) * 8];
            acc[db] = __builtin_amdgcn_mfma_f32_16x16x32_bf16(af.v, bf, acc[db], 0, 0, 0);
        }
    }

    float wbv[4], awd[4], aws[4];
    #pragma unroll
    for (int db = 0; db < 4; db++) {
        wbv[db] = Wb[db * 16 + col];
        awd[db] = Aw[db * 16 + col];
        aws[db] = Aw[OUT_DIM + db * 16 + col];
    }

    float pd[4] = {0.f, 0.f, 0.f, 0.f};
    float ps[4] = {0.f, 0.f, 0.f, 0.f};
    #pragma unroll
    for (int db = 0; db < 4; db++) {
        #pragma unroll
        for (int r = 0; r < 4; r++) {
            float v = acc[db][r] + wbv[db];
            int node = node0 + quad * 4 + r;
            if (node < N)
                Whb[(size_t)node * OUT_DIM + db * 16 + col] = f_to_bf16(v);
            pd[r] = fmaf(v, awd[db], pd[r]);
            ps[r] = fmaf(v, aws[db], ps[r]);
        }
    }
    #pragma unroll
    for (int r = 0; r < 4; r++) {
        float d_ = pd[r], s_ = ps[r];
        #pragma unroll
        for (int off = 1; off < 16; off <<= 1) {
            d_ += __shfl_xor(d_, off);
            s_ += __shfl_xor(s_, off);
        }
        int node = node0 + quad * 4 + r;
        if (col == 0 && node < N) {
            a_dst_arr[node] = d_;
            a_src_arr[node] = s_;
        }
    }
}

// ---------------------------------------------------------------------------
// K2: scatter into padded CSR — NO atomics, NO offs: pos = dst*MAXDEG + rank.
// Record: lo16 = src, hi16 = fp16(exp(leaky(logit))). 4 edges/thread.
// ---------------------------------------------------------------------------
__global__ __launch_bounds__(256) void gat_scatter(
    const int* __restrict__ src, const int* __restrict__ dst,
    const int* __restrict__ rank,
    const float* __restrict__ a_dst_arr, const float* __restrict__ a_src_arr,
    const float* __restrict__ Ab,
    uint_t* __restrict__ csr, int E)
{
    int base = (int)(blockIdx.x * blockDim.x + threadIdx.x) * 4;
    float ab = Ab[0];
    if (base + 4 <= E) {
        int4 s4 = *(const int4*)&src[base];
        int4 t4 = *(const int4*)&dst[base];
        int4 k4 = *(const int4*)&rank[base];
        int ss[4] = {s4.x, s4.y, s4.z, s4.w};
        int tt[4] = {t4.x, t4.y, t4.z, t4.w};
        int kk[4] = {k4.x, k4.y, k4.z, k4.w};
        #pragma unroll
        for (int i = 0; i < 4; i++) {
            float v = a_dst_arr[tt[i]] + a_src_arr[ss[i]] + ab;
            v = (v > 0.0f) ? v : 0.2f * v;
            float x = __expf(v);
            uint_t rec = (((uint_t)__half_as_ushort(__float2half(x))) << 16)
                       | (uint_t)(ss[i] & 0xffff);
            csr[tt[i] * MAXDEG + kk[i]] = rec;
        }
    } else {
        for (int e = base; e < E; e++) {
            int s = src[e];
            int t = dst[e];
            float v = a_dst_arr[t] + a_src_arr[s] + ab;
            v = (v > 0.0f) ? v : 0.2f * v;
            float x = __expf(v);
            uint_t rec = (((uint_t)__half_as_ushort(__float2half(x))) << 16)
                       | (uint_t)(s & 0xffff);
            csr[t * MAXDEG + rank[e]] = rec;
        }
    }
}

// ---------------------------------------------------------------------------
// K3: gather-aggregate. One wave per dst node. Half-wave per edge: lane
// el=lane>>5 picks edge slot, dl=lane&31 picks a bf16 dim-pair (uint load).
// 2 edges/step x 4-unroll = 8 concurrent 128 B gathers per wave.
// ---------------------------------------------------------------------------
__global__ __launch_bounds__(256) void gat_agg(
    const int* __restrict__ cnt, const uint_t* __restrict__ csr,
    const uint_t* __restrict__ Whb2, float* __restrict__ out, int N)
{
    int node = (int)((blockIdx.x * blockDim.x + threadIdx.x) >> 6);
    int lane = threadIdx.x & 63;
    if (node >= N) return;
    int u   = __builtin_amdgcn_readfirstlane(node);
    int deg = cnt[u];
    const uint_t* __restrict__ seg = csr + (size_t)u * MAXDEG;

    const int el = lane >> 5;   // edge slot within step
    const int dl = lane & 31;   // dim pair (dims 2*dl, 2*dl+1)

    float accx = 0.f, accy = 0.f, wsum = 0.f;

    int j = 0;
    for (; j + 8 <= deg; j += 8) {
        #pragma unroll
        for (int b = 0; b < 4; b++) {
            uint_t r = seg[j + b * 2 + el];
            int   s = (int)(r & 0xffffu);
            float w = __half2float(__ushort_as_half((ushort_t)(r >> 16)));
            uint_t p = Whb2[(size_t)s * 32 + dl];
            float fx = __uint_as_float(p << 16);
            float fy = __uint_as_float(p & 0xffff0000u);
            accx = fmaf(w, fx, accx);
            accy = fmaf(w, fy, accy);
            wsum += w;
        }
    }
    for (; j < deg; j += 2) {
        int e = j + el;
        if (e < deg) {
            uint_t r = seg[e];
            int   s = (int)(r & 0xffffu);
            float w = __half2float(__ushort_as_half((ushort_t)(r >> 16)));
            uint_t p = Whb2[(size_t)s * 32 + dl];
            float fx = __uint_as_float(p << 16);
            float fy = __uint_as_float(p & 0xffff0000u);
            accx = fmaf(w, fx, accx);
            accy = fmaf(w, fy, accy);
            wsum += w;
        }
    }

    // Combine the two half-wave edge slots.
    accx += __shfl_xor(accx, 32);
    accy += __shfl_xor(accy, 32);
    wsum += __shfl_xor(wsum, 32);

    float inv = (deg > 0) ? 1.0f / wsum : 0.0f;
    if (lane < 32) {
        float2 o = make_float2(accx * inv, accy * inv);
        *(float2*)&out[(size_t)u * OUT_DIM + dl * 2] = o;
    }
}

extern "C" void kernel_launch(void* const* d_in, const int* in_sizes, int n_in,
                              void* d_out, int out_size, void* d_ws, size_t ws_size,
                              hipStream_t stream)
{
    const float* h   = (const float*)d_in[0];
    const float* W_w = (const float*)d_in[1];
    const float* W_b = (const float*)d_in[2];
    const float* A_w = (const float*)d_in[3];
    const float* A_b = (const float*)d_in[4];
    const int*   src = (const int*)d_in[5];
    const int*   dst = (const int*)d_in[6];
    float* out = (float*)d_out;

    const int N = in_sizes[0] / IN_DIM;   // 50000
    const int E = in_sizes[5];            // 800000

    // Workspace: Whb[N*64 u16] | a_dst[N] | a_src[N] | cnt[N] | rank[E] | csr[N*MAXDEG u32]
    ushort_t* Whb   = (ushort_t*)d_ws;
    float* a_dst_a  = (float*)(Whb + (size_t)N * OUT_DIM);
    float* a_src_a  = a_dst_a + N;
    int*   cnt      = (int*)(a_src_a + N);
    int*   rank     = cnt + N;
    uint_t* csr     = (uint_t*)(rank + E);

    (void)hipMemsetAsync(cnt, 0, (size_t)N * sizeof(int), stream);

    {   // K1: fused histogram+rank (blocks [0,HB)) and MFMA projection (rest)
        int HB = (E + 1023) / 1024;                 // 4 edges/thread
        int waves = (N + 15) / 16;
        int PB = (waves + 3) / 4;                   // 4 waves/block
        gat_fused<<<HB + PB, 256, 0, stream>>>(h, W_w, W_b, A_w, Whb,
                                               a_dst_a, a_src_a, N,
                                               dst, cnt, rank, E, HB);
    }
    {   // K2: scatter (atomic-free, padded CSR)
        int grid = (E / 4 + 255) / 256;
        gat_scatter<<<grid, 256, 0, stream>>>(src, dst, rank, a_dst_a, a_src_a,
                                              A_b, csr, E);
    }
    {   // K3: gather-aggregate
        int grid = (N + 3) / 4;
        gat_agg<<<grid, 256, 0, stream>>>(cnt, csr, (const uint_t*)Whb, out, N);
    }
}